// Round 4
// baseline (370.661 us; speedup 1.0000x reference)
//
#include <hip/hip_runtime.h>

#define HDIM 20
#define BLOCK 256
#define LPE 4   // lanes per element; lane s owns units j = 4u+s, u=0..4

typedef __fp16 half2v __attribute__((ext_vector_type(2)));

static __device__ __forceinline__ float fdot2(half2v a, half2v b, float c) {
    return __builtin_amdgcn_fdot2(a, b, c, false);
}
static __device__ __forceinline__ half2v pk(float lo, float hi) {
    return __builtin_amdgcn_cvt_pkrtz(lo, hi);
}
// DPP quad_perm helper: compile-time pattern, full-rate VALU, no LDS pipe.
template <int CTRL>
static __device__ __forceinline__ float dppf(float x) {
    int xi = __builtin_bit_cast(int, x);
    int r = __builtin_amdgcn_update_dpp(0, xi, CTRL, 0xF, 0xF, true);
    return __builtin_bit_cast(float, r);
}
#define QP_BCAST0 0x00  // quad_perm:[0,0,0,0]
#define QP_BCAST1 0x55  // quad_perm:[1,1,1,1]
#define QP_BCAST2 0xAA  // quad_perm:[2,2,2,2]
#define QP_BCAST3 0xFF  // quad_perm:[3,3,3,3]
#define QP_XOR1   0xB1  // quad_perm:[1,0,3,2]
#define QP_XOR2   0x4E  // quad_perm:[2,3,0,1]

__global__ __launch_bounds__(BLOCK, 2) void gru_decoder_kernel(
    const float* __restrict__ hidden,
    const float* __restrict__ w_ih,
    const float* __restrict__ w_hh,
    const float* __restrict__ b_ih,
    const float* __restrict__ b_hh,
    const float* __restrict__ w_l,
    const float* __restrict__ b_l,
    const int*  __restrict__ step_ptr,
    float* __restrict__ out,
    int B)
{
    const int tid = threadIdx.x;
    const int s = tid & 3;                            // slice within element
    const int e = (blockIdx.x * BLOCK + tid) >> 2;    // element index
    if (e >= B) return;                               // exact fit; wave-uniform

    const int step = *step_ptr;

    // ---- loop-invariant weights, packed fp16 in REGISTERS (no in-loop LDS) ----
    half2v Wp[5][3][10];
    half2v XW[5][3];
    float  ar0[5], az0[5], ani0[5], anh0[5];
    float  wl0[5], wl1[5];
    #pragma unroll
    for (int u = 0; u < 5; ++u) {
        const int j = 4 * u + s;
        #pragma unroll
        for (int g = 0; g < 3; ++g) {
            const float* wr = w_hh + (g * 20 + j) * HDIM;
            #pragma unroll
            for (int p = 0; p < 10; ++p) {
                float2 w = *(const float2*)(wr + 2 * p);
                Wp[u][g][p] = pk(w.x, w.y);
            }
            float2 wi = *(const float2*)(w_ih + (g * 20 + j) * 2);
            XW[u][g] = pk(wi.x, wi.y);
        }
        ar0[u]  = b_ih[j]      + b_hh[j];
        az0[u]  = b_ih[20 + j] + b_hh[20 + j];
        ani0[u] = b_ih[40 + j];
        anh0[u] = b_hh[40 + j];
        wl0[u]  = w_l[j];
        wl1[u]  = w_l[20 + j];
    }
    const float bl0 = b_l[0], bl1 = b_l[1];

    // ---- state ----
    float hprev[5];
    half2v Hpair[10];                // Hpair[p] = (h[2p], h[2p+1])
    {
        const float* hb = hidden + (size_t)e * HDIM;
        #pragma unroll
        for (int u = 0; u < 5; ++u) hprev[u] = hb[4 * u + s];
        #pragma unroll
        for (int p = 0; p < 10; ++p) {
            float2 h2 = *(const float2*)(hb + 2 * p);
            Hpair[p] = pk(h2.x, h2.y);
        }
    }

    half2v xp = pk(0.f, 0.f);
    float* outp = out + (size_t)e * 2 * step;
    const float LOG2E = 1.4426950408889634f;

    for (int t = 0; t < step; t += 2) {
        #pragma unroll
        for (int tt = 0; tt < 2; ++tt) {
            float hnew[5];
            float py0 = 0.f, py1 = 0.f;
            #pragma unroll
            for (int u = 0; u < 5; ++u) {
                // r gate: 3 parallel sub-chains
                float arA = fdot2(XW[u][0], xp, ar0[u]);
                float arB = fdot2(Wp[u][0][4], Hpair[4], 0.f);
                float arC = fdot2(Wp[u][0][7], Hpair[7], 0.f);
                #pragma unroll
                for (int p = 0; p < 4; ++p) arA = fdot2(Wp[u][0][p], Hpair[p], arA);
                #pragma unroll
                for (int p = 5; p < 7; ++p) arB = fdot2(Wp[u][0][p], Hpair[p], arB);
                #pragma unroll
                for (int p = 8; p < 10; ++p) arC = fdot2(Wp[u][0][p], Hpair[p], arC);
                float ar = (arA + arB) + arC;
                // z gate
                float azA = fdot2(XW[u][1], xp, az0[u]);
                float azB = fdot2(Wp[u][1][4], Hpair[4], 0.f);
                float azC = fdot2(Wp[u][1][7], Hpair[7], 0.f);
                #pragma unroll
                for (int p = 0; p < 4; ++p) azA = fdot2(Wp[u][1][p], Hpair[p], azA);
                #pragma unroll
                for (int p = 5; p < 7; ++p) azB = fdot2(Wp[u][1][p], Hpair[p], azB);
                #pragma unroll
                for (int p = 8; p < 10; ++p) azC = fdot2(Wp[u][1][p], Hpair[p], azC);
                float az = (azA + azB) + azC;
                // n gate: hidden part separate (scaled by r), input part separate
                float anA = fdot2(Wp[u][2][0], Hpair[0], anh0[u]);
                float anB = fdot2(Wp[u][2][4], Hpair[4], 0.f);
                float anC = fdot2(Wp[u][2][7], Hpair[7], 0.f);
                #pragma unroll
                for (int p = 1; p < 4; ++p) anA = fdot2(Wp[u][2][p], Hpair[p], anA);
                #pragma unroll
                for (int p = 5; p < 7; ++p) anB = fdot2(Wp[u][2][p], Hpair[p], anB);
                #pragma unroll
                for (int p = 8; p < 10; ++p) anC = fdot2(Wp[u][2][p], Hpair[p], anC);
                float anH = (anA + anB) + anC;
                float anI = fdot2(XW[u][2], xp, ani0[u]);

                float r = __builtin_amdgcn_rcpf(1.f + __builtin_amdgcn_exp2f(-ar * LOG2E));
                float z = __builtin_amdgcn_rcpf(1.f + __builtin_amdgcn_exp2f(-az * LOG2E));
                float npre = anI + r * anH;
                float n = 1.f - 2.f * __builtin_amdgcn_rcpf(1.f + __builtin_amdgcn_exp2f(2.f * npre * LOG2E));
                float hv = n + z * (hprev[u] - n);
                hnew[u] = hv;
                py0 += hv * wl0[u];
                py1 += hv * wl1[u];
            }

            // y allreduce over the quad via DPP butterflies (VALU, no LDS pipe)
            py0 += dppf<QP_XOR1>(py0);
            py0 += dppf<QP_XOR2>(py0);
            py1 += dppf<QP_XOR1>(py1);
            py1 += dppf<QP_XOR2>(py1);
            float y0 = py0 + bl0;
            float y1 = py1 + bl1;

            if (s == 0) {
                float2 st; st.x = y0; st.y = y1;
                *(float2*)(outp + 2 * (step - 1 - (t + tt))) = st;   // reversed time
            }
            xp = pk(y0, y1);

            // h allgather via DPP quad broadcasts: unit j = 4u + d lives on quad-lane d
            #pragma unroll
            for (int u = 0; u < 5; ++u) {
                float h0 = dppf<QP_BCAST0>(hnew[u]);
                float h1 = dppf<QP_BCAST1>(hnew[u]);
                float h2 = dppf<QP_BCAST2>(hnew[u]);
                float h3 = dppf<QP_BCAST3>(hnew[u]);
                Hpair[2 * u + 0] = pk(h0, h1);
                Hpair[2 * u + 1] = pk(h2, h3);
                hprev[u] = hnew[u];
            }
        }
    }
}

extern "C" void kernel_launch(void* const* d_in, const int* in_sizes, int n_in,
                              void* d_out, int out_size, void* d_ws, size_t ws_size,
                              hipStream_t stream) {
    const float* hidden = (const float*)d_in[0];
    const float* w_ih   = (const float*)d_in[1];
    const float* w_hh   = (const float*)d_in[2];
    const float* b_ih   = (const float*)d_in[3];
    const float* b_hh   = (const float*)d_in[4];
    const float* w_l    = (const float*)d_in[5];
    const float* b_l    = (const float*)d_in[6];
    const int*   step   = (const int*)d_in[7];
    float* out = (float*)d_out;

    int B = in_sizes[0] / HDIM;                 // hidden is (1, B, 20)
    int grid = (B * LPE + BLOCK - 1) / BLOCK;   // 4 lanes per element

    gru_decoder_kernel<<<grid, BLOCK, 0, stream>>>(
        hidden, w_ih, w_hh, b_ih, b_hh, w_l, b_l, step, out, B);
}

// Round 5
// 188.429 us; speedup vs baseline: 1.9671x; 1.9671x over previous
//
#include <hip/hip_runtime.h>

#define HDIM 20
#define BLOCK 256

typedef __fp16 half8 __attribute__((ext_vector_type(8)));
typedef float  float4v __attribute__((ext_vector_type(4)));

static __device__ __forceinline__ float4v mfma16(half8 a, half8 b, float4v c) {
    return __builtin_amdgcn_mfma_f32_16x16x32_f16(a, b, c, 0, 0, 0);
}

// Layout summary (per wave = 16 elements):
//  A (weights, loop-invariant regs): 5 gate tiles + 1 y tile of 16x16x32 f16.
//    Global gate row r = 16T + 4*qr + i  ->  unit u = 4T+qr, type i in
//    {0:r(comb), 1:z(comb), 2:n-input(wx), 3:n-hidden(whh)}.  Bias in k=20.
//  B (h_t, rebuilt per step): B[k][elem], lane holds k=8q..8q+7 for elem=l&15.
//    k=20 is constant 1.0 (bias row); k=21..31 zero.
//  C/D: col=lane&15=elem, row=(l>>4)*4+reg -> lane (q=l>>4, e) gets unit 4T+q's
//    (ar,az,anI,anH) in regs 0..3 of tile T.  y tile: q==0 lanes get (y0,y1).

__global__ __launch_bounds__(BLOCK, 2) void gru_decoder_kernel(
    const float* __restrict__ hidden,
    const float* __restrict__ w_ih,
    const float* __restrict__ w_hh,
    const float* __restrict__ b_ih,
    const float* __restrict__ b_hh,
    const float* __restrict__ w_l,
    const float* __restrict__ b_l,
    const int*  __restrict__ step_ptr,
    float* __restrict__ out,
    int B)
{
    __shared__ __align__(16) __fp16 lds[4 * 16 * 40];   // 4 waves x 16 elems x 40 halfs (80B stride)

    const int tid = threadIdx.x;
    const int l   = tid & 63;
    const int wv  = tid >> 6;
    const int el  = l & 15;
    const int q   = l >> 4;
    const int e   = (blockIdx.x * 4 + wv) * 16 + el;
    const int step = *step_ptr;

    // ---- build A fragments (once) ----
    const int i_t = el & 3;    // gate type of this lane's A rows
    const int qr  = el >> 2;   // row-quad -> unit offset
    const int k0  = 8 * q;     // lane's k-slice

    half8 Afold[5], Azero[5], Ay;
    #pragma unroll
    for (int T = 0; T < 5; ++T) {
        const int u  = 4 * T + qr;
        const int rr = (i_t == 0) ? u : (i_t == 1) ? 20 + u : 40 + u;
        half8 hf, h0;
        #pragma unroll
        for (int j = 0; j < 8; ++j) {
            const int k = k0 + j;
            float a_f = 0.f, a_0 = 0.f;
            if (k < HDIM) {
                float wxv = w_ih[rr * 2 + 0] * w_l[k] + w_ih[rr * 2 + 1] * w_l[HDIM + k];
                float whv = w_hh[rr * HDIM + k];
                if (i_t <= 1)      { a_f = whv + wxv; a_0 = whv; }
                else if (i_t == 2) { a_f = wxv;       a_0 = 0.f; }
                else               { a_f = whv;       a_0 = whv; }
            } else if (k == HDIM) {
                float bx = w_ih[rr * 2 + 0] * b_l[0] + w_ih[rr * 2 + 1] * b_l[1];
                if (i_t <= 1)      { a_f = b_ih[rr] + b_hh[rr] + bx; a_0 = b_ih[rr] + b_hh[rr]; }
                else if (i_t == 2) { a_f = b_ih[rr] + bx;            a_0 = b_ih[rr]; }
                else               { a_f = b_hh[rr];                 a_0 = b_hh[rr]; }
            }
            hf[j] = (__fp16)a_f;
            h0[j] = (__fp16)a_0;
        }
        Afold[T] = hf;
        Azero[T] = h0;
    }
    {   // y tile: A row 0 = w_l row 0 (+b_l[0] at k=20), row 1 = w_l row 1, rest 0
        half8 hy;
        #pragma unroll
        for (int j = 0; j < 8; ++j) {
            const int k = k0 + j;
            float v = 0.f;
            if (el < 2) {
                if (k < HDIM)       v = w_l[el * HDIM + k];
                else if (k == HDIM) v = b_l[el];
            }
            hy[j] = (__fp16)v;
        }
        Ay = hy;
    }

    // ---- state init ----
    __fp16* elhp = &lds[(wv * 16 + el) * 40];
    float hprev[5];
    {
        const float* hb = hidden + (size_t)e * HDIM;
        #pragma unroll
        for (int T = 0; T < 5; ++T) {
            float hv = hb[4 * T + q];
            hprev[T] = hv;
            elhp[4 * T + q] = (__fp16)hv;
        }
        if (q == 2) {  // bias-1.0 row + zero pad (k=20..23)
            elhp[20] = (__fp16)1.f; elhp[21] = (__fp16)0.f;
            elhp[22] = (__fp16)0.f; elhp[23] = (__fp16)0.f;
        }
        if (q == 3) {  // zero pad k=24..31
            half8 z8 = {};
            *(half8*)(elhp + 24) = z8;
        }
    }
    half8 Bf = *(const half8*)(elhp + 8 * q);   // wave-synchronous: DS ops in-order per wave

    const float NLOG2E   = -1.4426950408889634f;
    const float TWOLOG2E =  2.8853900817779268f;

    auto do_step = [&](const half8* A) {
        float4v z4 = {0.f, 0.f, 0.f, 0.f};
        float4v C[5];
        #pragma unroll
        for (int T = 0; T < 5; ++T) C[T] = mfma16(A[T], Bf, z4);
        #pragma unroll
        for (int T = 0; T < 5; ++T) {
            float ar = C[T][0], az = C[T][1], anI = C[T][2], anH = C[T][3];
            float r = __builtin_amdgcn_rcpf(1.f + __builtin_amdgcn_exp2f(ar * NLOG2E));
            float z = __builtin_amdgcn_rcpf(1.f + __builtin_amdgcn_exp2f(az * NLOG2E));
            float npre = anI + r * anH;
            float n = 1.f - 2.f * __builtin_amdgcn_rcpf(1.f + __builtin_amdgcn_exp2f(npre * TWOLOG2E));
            float hv = n + z * (hprev[T] - n);        // (1-z)*n + z*h
            hprev[T] = hv;
            elhp[4 * T + q] = (__fp16)hv;
        }
        Bf = *(const half8*)(elhp + 8 * q);           // next step's B fragment
    };

    float* outp = out + (size_t)e * 2 * step;

    do_step(Azero);                                   // step 0 (x=0): h_0 -> h_1
    for (int t = 1; t < step; ++t) {
        float4v z4 = {0.f, 0.f, 0.f, 0.f};
        float4v cy = mfma16(Ay, Bf, z4);              // y_{t-1} = w_l . h_t + b_l
        if (q == 0) {
            float2 st; st.x = cy[0]; st.y = cy[1];
            *(float2*)(outp + 2 * (step - t)) = st;   // reversed time index (t-1)
        }
        do_step(Afold);                               // h_t -> h_{t+1}, x folded in
    }
    {   // final y_{step-1} from h_step
        float4v z4 = {0.f, 0.f, 0.f, 0.f};
        float4v cy = mfma16(Ay, Bf, z4);
        if (q == 0) {
            float2 st; st.x = cy[0]; st.y = cy[1];
            *(float2*)(outp + 0) = st;
        }
    }
}

extern "C" void kernel_launch(void* const* d_in, const int* in_sizes, int n_in,
                              void* d_out, int out_size, void* d_ws, size_t ws_size,
                              hipStream_t stream) {
    const float* hidden = (const float*)d_in[0];
    const float* w_ih   = (const float*)d_in[1];
    const float* w_hh   = (const float*)d_in[2];
    const float* b_ih   = (const float*)d_in[3];
    const float* b_hh   = (const float*)d_in[4];
    const float* w_l    = (const float*)d_in[5];
    const float* b_l    = (const float*)d_in[6];
    const int*   step   = (const int*)d_in[7];
    float* out = (float*)d_out;

    int B = in_sizes[0] / HDIM;     // hidden is (1, B, 20); B = 32768
    int grid = B / 64;              // 4 waves/block x 16 elements/wave

    gru_decoder_kernel<<<grid, BLOCK, 0, stream>>>(
        hidden, w_ih, w_hh, b_ih, b_hh, w_l, b_l, step, out, B);
}

// Round 6
// 171.468 us; speedup vs baseline: 2.1617x; 1.0989x over previous
//
#include <hip/hip_runtime.h>

#define HDIM 20
#define BLOCK 256

typedef __fp16 half8 __attribute__((ext_vector_type(8)));
typedef float  float4v __attribute__((ext_vector_type(4)));

static __device__ __forceinline__ float4v mfma16(half8 a, half8 b, float4v c) {
    return __builtin_amdgcn_mfma_f32_16x16x32_f16(a, b, c, 0, 0, 0);
}

// B-row permutation: k = 8q + i, i<5 -> unit 4i+q ; i=5,6 pad ; k=7 bias(=1.0).
// Lane (q,el) owns B rows k=8q..8q+7 of element el; its 5 h-units (4T+q from the
// C-layout) land at i=T -> per-step LDS update = b64+b16 write, read b128.
// A rows pre-scaled: r,z by -log2e (exp2 input direct), nI,nH by +2log2e (tanh
// via 1-2/(1+exp2(2x*log2e))).

__global__ __launch_bounds__(BLOCK, 2) void gru_decoder_kernel(
    const float* __restrict__ hidden,
    const float* __restrict__ w_ih,
    const float* __restrict__ w_hh,
    const float* __restrict__ b_ih,
    const float* __restrict__ b_hh,
    const float* __restrict__ w_l,
    const float* __restrict__ b_l,
    const int*  __restrict__ step_ptr,
    float* __restrict__ out,
    int B)
{
    __shared__ __align__(16) __fp16 lds[4 * 16 * 40];   // 80 B per element

    const int tid = threadIdx.x;
    const int l   = tid & 63;
    const int wv  = tid >> 6;
    const int el  = l & 15;
    const int q   = l >> 4;
    const int e   = (blockIdx.x * 4 + wv) * 16 + el;
    const int step = *step_ptr;

    const float NL2E = -1.4426950408889634f;   // r,z scale
    const float T2L2E = 2.8853900817779268f;   // n scale

    // ---- A fragments (once). Lane holds k=8q..8q+7; A row m=el of tile T is
    // gate row: unit 4T+(el>>2), type el&3 {0:r,1:z,2:nI,3:nH}. ----
    const int u_dst = el >> 2;   // + 4T below
    const int g     = el & 3;

    half8 Afold[5], Azero[5], Ay;
    #pragma unroll
    for (int T = 0; T < 5; ++T) {
        const int u  = 4 * T + u_dst;
        const int rr = (g == 0) ? u : (g == 1) ? 20 + u : 40 + u;
        const float sc = (g <= 1) ? NL2E : T2L2E;
        half8 hf, h0;
        #pragma unroll
        for (int j = 0; j < 8; ++j) {
            float af = 0.f, a0 = 0.f;
            if (j < 5) {
                const int uk = 4 * j + q;                 // permuted source unit
                float wx = w_ih[rr * 2 + 0] * w_l[uk] + w_ih[rr * 2 + 1] * w_l[HDIM + uk];
                float wh = w_hh[rr * HDIM + uk];
                if (g <= 1)      { af = wh + wx; a0 = wh; }
                else if (g == 2) { af = wx;      a0 = 0.f; }
                else             { af = wh;      a0 = wh; }
            } else if (j == 7 && q == 0) {                // bias column
                float bx = w_ih[rr * 2 + 0] * b_l[0] + w_ih[rr * 2 + 1] * b_l[1];
                if (g <= 1)      { af = b_ih[rr] + b_hh[rr] + bx; a0 = b_ih[rr] + b_hh[rr]; }
                else if (g == 2) { af = b_ih[rr] + bx;            a0 = b_ih[rr]; }
                else             { af = b_hh[rr];                 a0 = b_hh[rr]; }
            }
            hf[j] = (__fp16)(af * sc);
            h0[j] = (__fp16)(a0 * sc);
        }
        Afold[T] = hf;
        Azero[T] = h0;
    }
    {   // y tile (unscaled): row 0 = w_l row 0, row 1 = w_l row 1, bias at k=7
        half8 hy;
        #pragma unroll
        for (int j = 0; j < 8; ++j) {
            float v = 0.f;
            if (el < 2) {
                if (j < 5)                   v = w_l[el * HDIM + 4 * j + q];
                else if (j == 7 && q == 0)   v = b_l[el];
            }
            hy[j] = (__fp16)v;
        }
        Ay = hy;
    }

    // ---- state init: build lane's B slice in regs, write whole slice once ----
    __fp16* slice = &lds[(wv * 16 + el) * 40 + 8 * q];    // 16B-aligned
    float hprev[5];
    half8 Bf;
    {
        const float* hb = hidden + (size_t)e * HDIM;
        half8 b0;
        #pragma unroll
        for (int T = 0; T < 5; ++T) {
            float hv = hb[4 * T + q];
            hprev[T] = hv;
            b0[T] = (__fp16)hv;
        }
        b0[5] = (__fp16)0.f;
        b0[6] = (__fp16)0.f;
        b0[7] = (__fp16)((q == 0) ? 1.f : 0.f);           // bias row
        *(half8*)slice = b0;                               // includes static pads
        Bf = b0;
    }

    const float4v czero = {0.f, 0.f, 0.f, 0.f};
    typedef __fp16 half2v __attribute__((ext_vector_type(2)));
    typedef float  float2v __attribute__((ext_vector_type(2)));

    auto do_step = [&](const half8* A) {
        float4v C[5];
        #pragma unroll
        for (int T = 0; T < 5; ++T) C[T] = mfma16(A[T], Bf, czero);
        #pragma unroll
        for (int T = 0; T < 5; ++T) {
            // C = (-log2e*ar, -log2e*az, 2log2e*anI, 2log2e*anH)
            float r = __builtin_amdgcn_rcpf(1.f + __builtin_amdgcn_exp2f(C[T][0]));
            float z = __builtin_amdgcn_rcpf(1.f + __builtin_amdgcn_exp2f(C[T][1]));
            float npre2 = C[T][2] + r * C[T][3];
            float tn = __builtin_amdgcn_rcpf(1.f + __builtin_amdgcn_exp2f(npre2));
            float n = __builtin_fmaf(-2.f, tn, 1.f);
            float hv = __builtin_fmaf(z, hprev[T] - n, n);
            hprev[T] = hv;
        }
        // pack + 2-op LDS update (slots 0..4; 5..7 static)
        half2v p01 = __builtin_amdgcn_cvt_pkrtz(hprev[0], hprev[1]);
        half2v p23 = __builtin_amdgcn_cvt_pkrtz(hprev[2], hprev[3]);
        float2v d2; d2[0] = __builtin_bit_cast(float, p01); d2[1] = __builtin_bit_cast(float, p23);
        *(float2v*)slice = d2;
        slice[4] = (__fp16)hprev[4];
        Bf = *(const half8*)slice;        // wave-synchronous DS: in-order per wave
    };

    float* outp = out + (size_t)e * 2 * step;

    do_step(Azero);                                   // h_0 -> h_1
    for (int t = 1; t < step; ++t) {
        float4v cy = mfma16(Ay, Bf, czero);           // y_{t-1} = w_l . h_t + b_l
        if (q == 0) {
            float2 st; st.x = cy[0]; st.y = cy[1];
            *(float2*)(outp + 2 * (step - t)) = st;   // reversed time index
        }
        do_step(Afold);                               // h_t -> h_{t+1}
    }
    {   // final y_{step-1} from h_step
        float4v cy = mfma16(Ay, Bf, czero);
        if (q == 0) {
            float2 st; st.x = cy[0]; st.y = cy[1];
            *(float2*)(outp + 0) = st;
        }
    }
}

extern "C" void kernel_launch(void* const* d_in, const int* in_sizes, int n_in,
                              void* d_out, int out_size, void* d_ws, size_t ws_size,
                              hipStream_t stream) {
    const float* hidden = (const float*)d_in[0];
    const float* w_ih   = (const float*)d_in[1];
    const float* w_hh   = (const float*)d_in[2];
    const float* b_ih   = (const float*)d_in[3];
    const float* b_hh   = (const float*)d_in[4];
    const float* w_l    = (const float*)d_in[5];
    const float* b_l    = (const float*)d_in[6];
    const int*   step   = (const int*)d_in[7];
    float* out = (float*)d_out;

    int B = in_sizes[0] / HDIM;     // hidden is (1, B, 20); B = 32768
    int grid = B / 64;              // 4 waves/block x 16 elements/wave

    gru_decoder_kernel<<<grid, BLOCK, 0, stream>>>(
        hidden, w_ih, w_hh, b_ih, b_hh, w_l, b_l, step, out, B);
}

// Round 7
// 168.638 us; speedup vs baseline: 2.1980x; 1.0168x over previous
//
#include <hip/hip_runtime.h>

#define HDIM 20
#define BLOCK 256

typedef __fp16 half8 __attribute__((ext_vector_type(8)));
typedef __fp16 half2v __attribute__((ext_vector_type(2)));
typedef float  float4v __attribute__((ext_vector_type(4)));
typedef int    int4v  __attribute__((ext_vector_type(4)));

static __device__ __forceinline__ float4v mfma16(half8 a, half8 b, float4v c) {
    return __builtin_amdgcn_mfma_f32_16x16x32_f16(a, b, c, 0, 0, 0);
}

// KEY INVARIANT (why there is NO cross-lane traffic in the 200-step loop):
//   B-row permutation: k = 8q + i  <->  hidden unit 4i + q   (i<5; i=5,6 pad; k=7(q=0) bias=1).
//   C/D layout (m89): lane (q,el) holds D rows 4q..4q+3 of column el.
//   A rows arranged so tile T, row 4q'+g = unit 4T+q', gate type g in {r,z,nI,nH}
//   -> lane (q,el) computes h_new for units {4T+q}, which are EXACTLY its own
//      B rows k=8q+T. The "allgather" is the identity: pack own h to fp16, done.
// A rows pre-scaled: r,z by -log2e ; nI,nH by +2log2e (tanh via 1-2/(1+exp2)).

__global__ __launch_bounds__(BLOCK, 2) void gru_decoder_kernel(
    const float* __restrict__ hidden,
    const float* __restrict__ w_ih,
    const float* __restrict__ w_hh,
    const float* __restrict__ b_ih,
    const float* __restrict__ b_hh,
    const float* __restrict__ w_l,
    const float* __restrict__ b_l,
    const int*  __restrict__ step_ptr,
    float* __restrict__ out,
    int B)
{
    const int tid = threadIdx.x;
    const int l   = tid & 63;
    const int wv  = tid >> 6;
    const int el  = l & 15;
    const int q   = l >> 4;
    const int e   = (blockIdx.x * 4 + wv) * 16 + el;
    const int step = *step_ptr;

    const float NL2E  = -1.4426950408889634f;   // r,z scale
    const float T2L2E =  2.8853900817779268f;   // n scale

    // ---- A fragments (once). Lane holds k=8q..8q+7; A row m=el of tile T is
    // unit 4T+(el>>2), gate type el&3 {0:r,1:z,2:nI,3:nH}. ----
    const int u_dst = el >> 2;
    const int g     = el & 3;

    half8 Afold[5], Azero[5], Ay;
    #pragma unroll
    for (int T = 0; T < 5; ++T) {
        const int u  = 4 * T + u_dst;
        const int rr = (g == 0) ? u : (g == 1) ? 20 + u : 40 + u;
        const float sc = (g <= 1) ? NL2E : T2L2E;
        half8 hf, h0;
        #pragma unroll
        for (int j = 0; j < 8; ++j) {
            float af = 0.f, a0 = 0.f;
            if (j < 5) {
                const int uk = 4 * j + q;                 // permuted source unit
                float wx = w_ih[rr * 2 + 0] * w_l[uk] + w_ih[rr * 2 + 1] * w_l[HDIM + uk];
                float wh = w_hh[rr * HDIM + uk];
                if (g <= 1)      { af = wh + wx; a0 = wh; }
                else if (g == 2) { af = wx;      a0 = 0.f; }
                else             { af = wh;      a0 = wh; }
            } else if (j == 7 && q == 0) {                // bias column
                float bx = w_ih[rr * 2 + 0] * b_l[0] + w_ih[rr * 2 + 1] * b_l[1];
                if (g <= 1)      { af = b_ih[rr] + b_hh[rr] + bx; a0 = b_ih[rr] + b_hh[rr]; }
                else if (g == 2) { af = b_ih[rr] + bx;            a0 = b_ih[rr]; }
                else             { af = b_hh[rr];                 a0 = b_hh[rr]; }
            }
            hf[j] = (__fp16)(af * sc);
            h0[j] = (__fp16)(a0 * sc);
        }
        Afold[T] = hf;
        Azero[T] = h0;
    }
    {   // y tile (unscaled): row 0 = w_l row 0, row 1 = w_l row 1, bias at k=7
        half8 hy;
        #pragma unroll
        for (int j = 0; j < 8; ++j) {
            float v = 0.f;
            if (el < 2) {
                if (j < 5)                 v = w_l[el * HDIM + 4 * j + q];
                else if (j == 7 && q == 0) v = b_l[el];
            }
            hy[j] = (__fp16)v;
        }
        Ay = hy;
    }

    // constant word3 of the B fragment: halves (k=8q+6 -> 0, k=8q+7 -> bias)
    int w3const;
    {
        half2v c67; c67[0] = (__fp16)0.f; c67[1] = (__fp16)((q == 0) ? 1.f : 0.f);
        w3const = __builtin_bit_cast(int, c67);
    }

    // ---- state init: hprev fp32; Bf = own units packed (identity allgather) ----
    float hprev[5];
    half8 Bf;
    {
        const float* hb = hidden + (size_t)e * HDIM;
        #pragma unroll
        for (int T = 0; T < 5; ++T) hprev[T] = hb[4 * T + q];
        int4v bi;
        bi[0] = __builtin_bit_cast(int, __builtin_amdgcn_cvt_pkrtz(hprev[0], hprev[1]));
        bi[1] = __builtin_bit_cast(int, __builtin_amdgcn_cvt_pkrtz(hprev[2], hprev[3]));
        bi[2] = __builtin_bit_cast(int, __builtin_amdgcn_cvt_pkrtz(hprev[4], 0.f));
        bi[3] = w3const;
        Bf = __builtin_bit_cast(half8, bi);
    }

    const float4v czero = {0.f, 0.f, 0.f, 0.f};

    auto do_step = [&](const half8* A) {
        float4v C[5];
        #pragma unroll
        for (int T = 0; T < 5; ++T) C[T] = mfma16(A[T], Bf, czero);
        #pragma unroll
        for (int T = 0; T < 5; ++T) {
            // C = (-log2e*ar, -log2e*az, 2log2e*anI, 2log2e*anH)
            float r = __builtin_amdgcn_rcpf(1.f + __builtin_amdgcn_exp2f(C[T][0]));
            float z = __builtin_amdgcn_rcpf(1.f + __builtin_amdgcn_exp2f(C[T][1]));
            float npre2 = __builtin_fmaf(r, C[T][3], C[T][2]);
            float tn = __builtin_amdgcn_rcpf(1.f + __builtin_amdgcn_exp2f(npre2));
            float n = __builtin_fmaf(-2.f, tn, 1.f);
            hprev[T] = __builtin_fmaf(z, hprev[T] - n, n);   // (1-z)*n + z*h
        }
        // rebuild B fragment from own registers — no LDS, no shuffles
        int4v bi;
        bi[0] = __builtin_bit_cast(int, __builtin_amdgcn_cvt_pkrtz(hprev[0], hprev[1]));
        bi[1] = __builtin_bit_cast(int, __builtin_amdgcn_cvt_pkrtz(hprev[2], hprev[3]));
        bi[2] = __builtin_bit_cast(int, __builtin_amdgcn_cvt_pkrtz(hprev[4], 0.f));
        bi[3] = w3const;
        Bf = __builtin_bit_cast(half8, bi);
    };

    float* outp = out + (size_t)e * 2 * step;

    do_step(Azero);                                   // h_0 -> h_1  (x=0 step)
    for (int t = 1; t < step; ++t) {
        float4v cy = mfma16(Ay, Bf, czero);           // y_{t-1} = w_l . h_t + b_l
        if (q == 0) {
            float2 st; st.x = cy[0]; st.y = cy[1];
            *(float2*)(outp + 2 * (step - t)) = st;   // reversed time index
        }
        do_step(Afold);                               // h_t -> h_{t+1} (x folded)
    }
    {   // final y_{step-1} from h_step
        float4v cy = mfma16(Ay, Bf, czero);
        if (q == 0) {
            float2 st; st.x = cy[0]; st.y = cy[1];
            *(float2*)(outp + 0) = st;
        }
    }
}

extern "C" void kernel_launch(void* const* d_in, const int* in_sizes, int n_in,
                              void* d_out, int out_size, void* d_ws, size_t ws_size,
                              hipStream_t stream) {
    const float* hidden = (const float*)d_in[0];
    const float* w_ih   = (const float*)d_in[1];
    const float* w_hh   = (const float*)d_in[2];
    const float* b_ih   = (const float*)d_in[3];
    const float* b_hh   = (const float*)d_in[4];
    const float* w_l    = (const float*)d_in[5];
    const float* b_l    = (const float*)d_in[6];
    const int*   step   = (const int*)d_in[7];
    float* out = (float*)d_out;

    int B = in_sizes[0] / HDIM;     // hidden is (1, B, 20); B = 32768
    int grid = B / 64;              // 4 waves/block x 16 elements/wave

    gru_decoder_kernel<<<grid, BLOCK, 0, stream>>>(
        hidden, w_ih, w_hh, b_ih, b_hh, w_l, b_l, step, out, B);
}